// Round 1
// baseline (954.232 us; speedup 1.0000x reference)
//
#include <hip/hip_runtime.h>

// Problem constants (from reference): B=2, L=2048, D=1024, H=16, DK=64
#define B_  2
#define L_  2048
#define D_  1024
#define H_  16
#define DK_ 64
#define SCALE_ 0.35355339059327373f   // 64^-0.25

typedef _Float16 f16;
typedef __attribute__((ext_vector_type(8))) _Float16 f16x8;
typedef __attribute__((ext_vector_type(4))) _Float16 f16x4;
typedef __attribute__((ext_vector_type(4))) float    f32x4;

#define AS1C(p) ((const __attribute__((address_space(1))) void*)(p))
#define AS3(p)  ((__attribute__((address_space(3))) void*)(p))

// ---------------------------------------------------------------------------
// fp32 -> fp16 conversion (memory-bound, vectorized 4 elems/thread)
// ---------------------------------------------------------------------------
__global__ void cvt_f32_f16(const float* __restrict__ in, f16* __restrict__ out, int n) {
    int i = (blockIdx.x * blockDim.x + threadIdx.x) * 4;
    if (i < n) {
        float4 v = *(const float4*)&in[i];
        f16x4 o;
        o[0] = (f16)v.x; o[1] = (f16)v.y; o[2] = (f16)v.z; o[3] = (f16)v.w;
        *(f16x4*)&out[i] = o;
    }
}

// ---------------------------------------------------------------------------
// GEMM: C[M,N] = alpha * A[M,K] @ B[N,K]^T   (both operands row-major, K contig)
// m97-style: 128x128 tile, BK=32, global_load_lds width 16, mfma 16x16x32 f16.
// 4 waves in 2x2; each wave owns a 64x64 sub-tile (4x4 frags of 16x16).
// ---------------------------------------------------------------------------
template <typename OutT>
__global__ __launch_bounds__(256) void gemm_bt(
    const f16* __restrict__ A, const f16* __restrict__ Bm, OutT* __restrict__ C,
    int M, int N, int Kd, float alpha)
{
    __shared__ f16 As[128 * 32];
    __shared__ f16 Bs[128 * 32];

    const int tid  = threadIdx.x;
    const int lane = tid & 63;
    const int w    = tid >> 6;
    const int quad = lane >> 4;
    const int l16  = lane & 15;
    const int wm   = w & 1, wn = w >> 1;
    const int m0   = blockIdx.y * 128;
    const int n0   = blockIdx.x * 128;

    f32x4 acc[4][4] = {};

    for (int k0 = 0; k0 < Kd; k0 += 32) {
        // stage A,B tiles: 128 rows x 32 halfs (64 B) = 512 chunks of 16 B each
#pragma unroll
        for (int it = 0; it < 2; ++it) {
            int c    = tid + it * 256;        // chunk id; LDS dst = base + lane*16 (contig)
            int row  = c >> 2;
            int koff = (c & 3) * 8;           // halfs
            __builtin_amdgcn_global_load_lds(AS1C(&A[(size_t)(m0 + row) * Kd + k0 + koff]),
                                             AS3(&As[c * 8]), 16, 0, 0);
            __builtin_amdgcn_global_load_lds(AS1C(&Bm[(size_t)(n0 + row) * Kd + k0 + koff]),
                                             AS3(&Bs[c * 8]), 16, 0, 0);
        }
        __syncthreads();   // drains vmcnt+lgkmcnt

        f16x8 af[4], bf[4];
#pragma unroll
        for (int i = 0; i < 4; ++i) {
            af[i] = *(const f16x8*)&As[(wm * 64 + i * 16 + l16) * 32 + quad * 8];
            bf[i] = *(const f16x8*)&Bs[(wn * 64 + i * 16 + l16) * 32 + quad * 8];
        }
#pragma unroll
        for (int i = 0; i < 4; ++i)
#pragma unroll
            for (int j = 0; j < 4; ++j)
                acc[i][j] = __builtin_amdgcn_mfma_f32_16x16x32_f16(af[i], bf[j], acc[i][j], 0, 0, 0);
        __syncthreads();
    }

    // epilogue: C/D layout col = lane&15, row = quad*4 + reg
#pragma unroll
    for (int i = 0; i < 4; ++i)
#pragma unroll
        for (int j = 0; j < 4; ++j)
#pragma unroll
            for (int r = 0; r < 4; ++r) {
                int row = m0 + wm * 64 + i * 16 + quad * 4 + r;
                int col = n0 + wn * 64 + j * 16 + l16;
                C[(size_t)row * N + col] = (OutT)(acc[i][j][r] * alpha);
            }
}

// ---------------------------------------------------------------------------
// Flash attention: per block = (b, h, 64-row Q tile); 4 waves x 16 Q-rows.
// Q,K pre-scaled by SCALE in the projection GEMMs. posbias added in fp32.
// Online softmax state per row; P->A-layout via padded LDS round-trip;
// V staged transposed (VT[n][k]) in padded LDS for the B operand of PV.
// ---------------------------------------------------------------------------
__global__ __launch_bounds__(256) void attn_kernel(
    const f16* __restrict__ Q, const f16* __restrict__ K, const f16* __restrict__ V,
    const float* __restrict__ bias, f16* __restrict__ ctx)
{
    const int qt = blockIdx.x & 31;          // L/64 = 32 q-tiles
    const int h  = (blockIdx.x >> 5) & 15;
    const int b  = blockIdx.x >> 9;
    const int q0 = qt * 64;

    const int tid  = threadIdx.x;
    const int w    = tid >> 6;
    const int lane = tid & 63;
    const int quad = lane >> 4;
    const int l16  = lane & 15;

    __shared__ f16 VT[64][72];               // V^T tile, +8 half pad (2-way banks = free)
    __shared__ f16 P[4][16][72];             // per-wave P tile, same pad

    const size_t bh = (size_t)b * L_ * D_ + (size_t)h * DK_;

    // Q fragments for this wave's 16 rows (held in regs for whole block)
    f16x8 qf[2];
    {
        const size_t qrow = (size_t)(q0 + w * 16 + l16);
#pragma unroll
        for (int ks = 0; ks < 2; ++ks)
            qf[ks] = *(const f16x8*)&Q[bh + qrow * D_ + ks * 32 + quad * 8];
    }

    f32x4 oacc[4] = {};                      // 4 n-groups (DK cols) x 4 rows
    float m_r[4], l_r[4];
#pragma unroll
    for (int r = 0; r < 4; ++r) { m_r[r] = -1e30f; l_r[r] = 0.f; }

    const float* biasrow = bias + ((size_t)(b * H_ + h) * L_ + q0 + w * 16) * L_;

    for (int j0 = 0; j0 < L_; j0 += 64) {
        // ---- stage V^T tile cooperatively (coalesced 16B global reads) ----
        {
            int r  = tid >> 2;
            int c0 = (tid & 3) * 16;
            f16x8 v0 = *(const f16x8*)&V[bh + (size_t)(j0 + r) * D_ + c0];
            f16x8 v1 = *(const f16x8*)&V[bh + (size_t)(j0 + r) * D_ + c0 + 8];
#pragma unroll
            for (int i = 0; i < 8; ++i) {
                VT[c0 + i][r]     = v0[i];
                VT[c0 + 8 + i][r] = v1[i];
            }
        }

        // ---- S = Q K^T (16x64 per wave), direct global K frags ----
        f32x4 s[4];
#pragma unroll
        for (int g = 0; g < 4; ++g) {
            const size_t krow = (size_t)(j0 + g * 16 + l16);
            f16x8 kf0 = *(const f16x8*)&K[bh + krow * D_ + quad * 8];
            f16x8 kf1 = *(const f16x8*)&K[bh + krow * D_ + 32 + quad * 8];
            f32x4 a = {};
            a = __builtin_amdgcn_mfma_f32_16x16x32_f16(qf[0], kf0, a, 0, 0, 0);
            a = __builtin_amdgcn_mfma_f32_16x16x32_f16(qf[1], kf1, a, 0, 0, 0);
            s[g] = a;
        }

        // ---- + posbias (fp32) ----
#pragma unroll
        for (int g = 0; g < 4; ++g)
#pragma unroll
            for (int r = 0; r < 4; ++r)
                s[g][r] += biasrow[(size_t)(quad * 4 + r) * L_ + j0 + g * 16 + l16];

        // ---- online softmax (rows live in 16-lane groups: row = quad*4+reg) ----
        float alpha[4];
#pragma unroll
        for (int r = 0; r < 4; ++r) {
            float mx = fmaxf(fmaxf(s[0][r], s[1][r]), fmaxf(s[2][r], s[3][r]));
#pragma unroll
            for (int off = 1; off < 16; off <<= 1)
                mx = fmaxf(mx, __shfl_xor(mx, off, 64));
            float mi = fmaxf(m_r[r], mx);
            alpha[r] = __expf(m_r[r] - mi);
            m_r[r]   = mi;
        }
#pragma unroll
        for (int g = 0; g < 4; ++g)
#pragma unroll
            for (int r = 0; r < 4; ++r)
                s[g][r] = __expf(s[g][r] - m_r[r]);
#pragma unroll
        for (int r = 0; r < 4; ++r) {
            float sm = s[0][r] + s[1][r] + s[2][r] + s[3][r];
#pragma unroll
            for (int off = 1; off < 16; off <<= 1)
                sm += __shfl_xor(sm, off, 64);
            l_r[r] = l_r[r] * alpha[r] + sm;
        }
#pragma unroll
        for (int g = 0; g < 4; ++g)
#pragma unroll
            for (int r = 0; r < 4; ++r)
                oacc[g][r] *= alpha[r];

        // ---- P (fp16) -> LDS in C-layout; read back in A-layout ----
#pragma unroll
        for (int g = 0; g < 4; ++g)
#pragma unroll
            for (int r = 0; r < 4; ++r)
                P[w][quad * 4 + r][g * 16 + l16] = (f16)s[g][r];

        __syncthreads();   // VT visible to all waves + P lgkm drained

        // ---- O += P V ----
#pragma unroll
        for (int ks = 0; ks < 2; ++ks) {
            f16x8 pf = *(const f16x8*)&P[w][l16][ks * 32 + quad * 8];
#pragma unroll
            for (int g = 0; g < 4; ++g) {
                f16x8 vf = *(const f16x8*)&VT[g * 16 + l16][ks * 32 + quad * 8];
                oacc[g] = __builtin_amdgcn_mfma_f32_16x16x32_f16(pf, vf, oacc[g], 0, 0, 0);
            }
        }
        __syncthreads();   // all reads done before next tile restages VT
    }

    // ---- epilogue: ctx[b, q, h*DK + c] = O / l ----
#pragma unroll
    for (int g = 0; g < 4; ++g)
#pragma unroll
        for (int r = 0; r < 4; ++r) {
            size_t row = (size_t)(q0 + w * 16 + quad * 4 + r);
            ctx[(size_t)b * L_ * D_ + row * D_ + h * DK_ + g * 16 + l16] =
                (f16)(oacc[g][r] / l_r[r]);
        }
}

// ---------------------------------------------------------------------------
// launcher
// ---------------------------------------------------------------------------
extern "C" void kernel_launch(void* const* d_in, const int* in_sizes, int n_in,
                              void* d_out, int out_size, void* d_ws, size_t ws_size,
                              hipStream_t stream)
{
    const float* query = (const float*)d_in[0];
    const float* key   = (const float*)d_in[1];
    const float* value = (const float*)d_in[2];
    const float* pbias = (const float*)d_in[3];
    const float* Wq    = (const float*)d_in[4];
    const float* Wk    = (const float*)d_in[5];
    const float* Wv    = (const float*)d_in[6];
    const float* Wo    = (const float*)d_in[7];
    float* out = (float*)d_out;

    char* ws = (char*)d_ws;
    // workspace layout (needs 64 MiB)
    f16* q16  = (f16*)(ws + 0);           // 4096x1024 halfs = 8 MiB each
    f16* k16  = (f16*)(ws + 8388608);
    f16* v16  = (f16*)(ws + 16777216);
    f16* wq16 = (f16*)(ws + 25165824);    // 1024x1024 halfs = 2 MiB each
    f16* wk16 = (f16*)(ws + 27262976);
    f16* wv16 = (f16*)(ws + 29360128);
    f16* wo16 = (f16*)(ws + 31457280);
    f16* Qs   = (f16*)(ws + 33554432);
    f16* Ks   = (f16*)(ws + 41943040);
    f16* Vs   = (f16*)(ws + 50331648);
    f16* ctx  = (f16*)(ws + 58720256);

    const int ML = B_ * L_;               // 4096
    const int nBig = ML * D_;             // 4,194,304
    const int nW   = D_ * D_;             // 1,048,576

    cvt_f32_f16<<<dim3((nBig / 4 + 255) / 256), 256, 0, stream>>>(query, q16, nBig);
    cvt_f32_f16<<<dim3((nBig / 4 + 255) / 256), 256, 0, stream>>>(key,   k16, nBig);
    cvt_f32_f16<<<dim3((nBig / 4 + 255) / 256), 256, 0, stream>>>(value, v16, nBig);
    cvt_f32_f16<<<dim3((nW / 4 + 255) / 256), 256, 0, stream>>>(Wq, wq16, nW);
    cvt_f32_f16<<<dim3((nW / 4 + 255) / 256), 256, 0, stream>>>(Wk, wk16, nW);
    cvt_f32_f16<<<dim3((nW / 4 + 255) / 256), 256, 0, stream>>>(Wv, wv16, nW);
    cvt_f32_f16<<<dim3((nW / 4 + 255) / 256), 256, 0, stream>>>(Wo, wo16, nW);

    dim3 gg(D_ / 128, ML / 128);          // (8, 32)
    gemm_bt<f16><<<gg, 256, 0, stream>>>(q16, wq16, Qs, ML, D_, D_, SCALE_);
    gemm_bt<f16><<<gg, 256, 0, stream>>>(k16, wk16, Ks, ML, D_, D_, SCALE_);
    gemm_bt<f16><<<gg, 256, 0, stream>>>(v16, wv16, Vs, ML, D_, D_, 1.0f);

    attn_kernel<<<dim3(B_ * H_ * (L_ / 64)), 256, 0, stream>>>(Qs, Ks, Vs, pbias, ctx);

    gemm_bt<float><<<gg, 256, 0, stream>>>(ctx, wo16, out, ML, D_, D_, 1.0f);
}